// Round 6
// baseline (183.401 us; speedup 1.0000x reference)
//
#include <hip/hip_runtime.h>
#include <hip/hip_bf16.h>
#include <math.h>

// B=2, T=2048, D=1024, H=16, hd=64. fp32 in/out.
// Round 19: attn arithmetic-intensity attack. R13-R18: attn pinned at ~43us
// across dbuf/KT/swizzle/occupancy variants -> shared-resource floor. Model:
// LDS datapath ~26us/CU (18 b128 reads per wave-tile, each K/V read feeds
// ONE MFMA; 4 waves re-read the full 16KB tile for only 16 queries each).
// Fix: 32 queries/wave (two 16-row Q fragments), 128 q/block, grid (32,16).
// Each kb/vb LDS read now feeds 2 MFMAs -> LDS bytes/work halved. K/V
// staging per query halved. LDS 34.4KB, VGPR ~110.
// Ledger: R14 swizzle free; R15 dbuf null->dropped; R16 BK=64 regress->
// reverted; cvt_pk kept; R17 LDS swizzle in GEMMs kept; R18 XCD swizzle
// kept, occupancy theory FALSIFIED (24.5% unchanged at 25.6KB LDS).
// ws (MB): xb@0[8] Wqt@8[2] Wkt@10[2] Wvt@12[2] Wot@14[2]
// Qb@16[8] Kb@24[8] VbT@32[8] Yb@40[8] = 48 MB.

#define Bsz  2
#define Tseq 2048
#define Dm   1024
#define NH   16
#define HD   64

typedef short bf16x8 __attribute__((ext_vector_type(8)));
typedef float floatx4 __attribute__((ext_vector_type(4)));

__device__ __forceinline__ unsigned short f2bf(float f) {
    __hip_bfloat16 h = __float2bfloat16(f);
    return *reinterpret_cast<unsigned short*>(&h);
}

// async global->LDS, 16 B per lane. LDS dest must be waveBase + lane*16.
__device__ __forceinline__ void lds16(unsigned short* lds, const unsigned short* g) {
    __builtin_amdgcn_global_load_lds(
        (const __attribute__((address_space(1))) void*)g,
        (__attribute__((address_space(3))) void*)lds, 16, 0, 0);
}

// ---------------- prep: W transpose-cast (z<4) + x cast (z>=4) ---------------
__global__ __launch_bounds__(256) void prep(const float* __restrict__ x,
                                            const float* __restrict__ W0,
                                            const float* __restrict__ W1,
                                            const float* __restrict__ W2,
                                            const float* __restrict__ W3,
                                            unsigned short* __restrict__ xb,
                                            unsigned short* __restrict__ T0,
                                            unsigned short* __restrict__ T1,
                                            unsigned short* __restrict__ T2,
                                            unsigned short* __restrict__ T3) {
    __shared__ float t[64][65];
    const int z = blockIdx.z;
    if (z >= 4) {  // cast x
        const int bi = (z - 4) * 256 + blockIdx.y * 16 + blockIdx.x;
        const size_t i = (size_t)bi * 256 + threadIdx.x;
        const float4 v = ((const float4*)x)[i];
        ushort4 o;
        o.x = f2bf(v.x); o.y = f2bf(v.y); o.z = f2bf(v.z); o.w = f2bf(v.w);
        ((ushort4*)xb)[i] = o;
        return;
    }
    const float* W = (z == 0) ? W0 : (z == 1) ? W1 : (z == 2) ? W2 : W3;
    unsigned short* T = (z == 0) ? T0 : (z == 1) ? T1 : (z == 2) ? T2 : T3;
    const int k0 = blockIdx.y * 64, n0 = blockIdx.x * 64;
    const int row = threadIdx.x >> 6, col = threadIdx.x & 63;
#pragma unroll
    for (int p = 0; p < 16; ++p)
        t[p * 4 + row][col] = W[(size_t)(k0 + p * 4 + row) * Dm + n0 + col];
    __syncthreads();
#pragma unroll
    for (int p = 0; p < 16; ++p)
        T[(size_t)(n0 + p * 4 + row) * Dm + k0 + col] = f2bf(t[col][p * 4 + row]);
}

// ---------------- bf16 MFMA GEMM mainloop (128x128, BK=32, swizzled) ---------
__device__ __forceinline__ void gemm128_mainloop(const unsigned short* __restrict__ A,
                                                 const unsigned short* __restrict__ Bt,
                                                 int K, int m0, int n0,
                                                 unsigned short* As, unsigned short* Bs,
                                                 floatx4 acc[4][4]) {
    const int tid = threadIdx.x;
    const int lane = tid & 63, wave = tid >> 6;
    const int l15 = lane & 15, quad = lane >> 4;
    const int wm = (wave >> 1) * 64, wn = (wave & 1) * 64;

    const int qsw = (quad ^ ((l15 >> 1) & 3)) * 8;

    for (int k0 = 0; k0 < K; k0 += 32) {
        __syncthreads();
#pragma unroll
        for (int c = 0; c < 2; ++c) {
            const int idx = c * 256 + tid;
            const int row = idx >> 2, kc = (idx & 3) * 8;
            const int sk = ((idx & 3) ^ ((row >> 1) & 3)) * 8;
            lds16(&As[row * 32 + kc], A + (size_t)(m0 + row) * K + k0 + sk);
            lds16(&Bs[row * 32 + kc], Bt + (size_t)(n0 + row) * K + k0 + sk);
        }
        __syncthreads();
        bf16x8 af[4], bfr[4];
#pragma unroll
        for (int i = 0; i < 4; ++i)
            af[i] = *(const bf16x8*)&As[(wm + i * 16 + l15) * 32 + qsw];
#pragma unroll
        for (int j = 0; j < 4; ++j)
            bfr[j] = *(const bf16x8*)&Bs[(wn + j * 16 + l15) * 32 + qsw];
#pragma unroll
        for (int i = 0; i < 4; ++i)
#pragma unroll
            for (int j = 0; j < 4; ++j)
                acc[i][j] = __builtin_amdgcn_mfma_f32_16x16x32_bf16(af[i], bfr[j], acc[i][j], 0, 0, 0);
    }
}

// QKV split over grid.z: z selects weight/output. Q scaled 0.125*log2e.
// z==2 (V) writes the transposed VbT [bh][d][tok] directly.
// XCD-swizzled block map (m-grouped).
__global__ __launch_bounds__(256) void gemm_qkv(const unsigned short* __restrict__ xb,
                                                const unsigned short* __restrict__ Wqt,
                                                const unsigned short* __restrict__ Wkt,
                                                const unsigned short* __restrict__ Wvt,
                                                unsigned short* __restrict__ Qb,
                                                unsigned short* __restrict__ Kb,
                                                unsigned short* __restrict__ VbT) {
    __shared__ unsigned short As[128 * 32];
    __shared__ unsigned short Bs[128 * 32];
    const int z = blockIdx.z;
    const unsigned short* Bt = (z == 0) ? Wqt : (z == 1) ? Wkt : Wvt;
    const float scale = (z == 0) ? (0.125f * 1.4426950408889634f) : 1.0f;

    const int wg = blockIdx.x + 8 * blockIdx.y;   // 0..255 within z-plane
    const int m_idx = (wg & 7) * 4 + (wg >> 6);   // 0..31
    const int n_idx = (wg >> 3) & 7;              // 0..7
    const int m0 = m_idx * 128, n0 = n_idx * 128;

    floatx4 acc[4][4];
#pragma unroll
    for (int i = 0; i < 4; ++i)
#pragma unroll
        for (int j = 0; j < 4; ++j) acc[i][j] = (floatx4){0.f, 0.f, 0.f, 0.f};

    gemm128_mainloop(xb, Bt, Dm, m0, n0, As, Bs, acc);

    const int lane = threadIdx.x & 63, wave = threadIdx.x >> 6;
    const int l15 = lane & 15, quad = lane >> 4;
    const int wm = (wave >> 1) * 64, wn = (wave & 1) * 64;

    if (z == 2) {
#pragma unroll
        for (int i = 0; i < 4; ++i)
#pragma unroll
            for (int j = 0; j < 4; ++j) {
                const int col = n0 + wn + j * 16 + l15;
                const int hh = col >> 6, dd = col & 63;
                const int tok = m0 + wm + i * 16 + quad * 4;
                const int bb = tok >> 11, tl = tok & (Tseq - 1);
                ushort4 o;
                o.x = f2bf(acc[i][j][0]); o.y = f2bf(acc[i][j][1]);
                o.z = f2bf(acc[i][j][2]); o.w = f2bf(acc[i][j][3]);
                *(ushort4*)&VbT[((size_t)((bb * NH + hh) * HD + dd)) * Tseq + tl] = o;
            }
        return;
    }
    unsigned short* C = (z == 0) ? Qb : Kb;
#pragma unroll
    for (int i = 0; i < 4; ++i)
#pragma unroll
        for (int j = 0; j < 4; ++j)
#pragma unroll
            for (int r = 0; r < 4; ++r) {
                const int row = m0 + wm + i * 16 + quad * 4 + r;
                const int col = n0 + wn + j * 16 + l15;
                C[(size_t)row * Dm + col] = f2bf(acc[i][j][r] * scale);
            }
}

// Final GEMM: Yb @ Wo -> fp32 out. 128x64 tiles, BK=32, swizzled LDS,
// XCD-swizzled block map (m-grouped like gemm_qkv).
__global__ __launch_bounds__(256) void gemm_out(const unsigned short* __restrict__ Yb,
                                                const unsigned short* __restrict__ Wot,
                                                float* __restrict__ out) {
    __shared__ unsigned short As[128 * 32];
    __shared__ unsigned short Bs[64 * 32];
    const int wg = blockIdx.x + 16 * blockIdx.y;  // 0..511
    const int m_idx = (wg & 7) * 4 + (wg >> 7);   // 0..31
    const int n_idx = (wg >> 3) & 15;             // 0..15
    const int m0 = m_idx * 128, n0 = n_idx * 64;
    const int tid = threadIdx.x;
    const int lane = tid & 63, wave = tid >> 6;
    const int l15 = lane & 15, quad = lane >> 4;
    const int wm = (wave >> 1) * 64, wn = (wave & 1) * 32;
    const int qsw = (quad ^ ((l15 >> 1) & 3)) * 8;

    floatx4 acc[4][2];
#pragma unroll
    for (int i = 0; i < 4; ++i)
#pragma unroll
        for (int j = 0; j < 2; ++j) acc[i][j] = (floatx4){0.f, 0.f, 0.f, 0.f};

    for (int k0 = 0; k0 < Dm; k0 += 32) {
        __syncthreads();
#pragma unroll
        for (int c = 0; c < 2; ++c) {
            const int idx = c * 256 + tid;
            const int row = idx >> 2, kc = (idx & 3) * 8;
            const int sk = ((idx & 3) ^ ((row >> 1) & 3)) * 8;
            lds16(&As[row * 32 + kc], Yb + (size_t)(m0 + row) * Dm + k0 + sk);
        }
        {
            const int row = tid >> 2, kc = (tid & 3) * 8;
            const int sk = ((tid & 3) ^ ((row >> 1) & 3)) * 8;
            lds16(&Bs[row * 32 + kc], Wot + (size_t)(n0 + row) * Dm + k0 + sk);
        }
        __syncthreads();
        bf16x8 af[4], bfr[2];
#pragma unroll
        for (int i = 0; i < 4; ++i)
            af[i] = *(const bf16x8*)&As[(wm + i * 16 + l15) * 32 + qsw];
#pragma unroll
        for (int j = 0; j < 2; ++j)
            bfr[j] = *(const bf16x8*)&Bs[(wn + j * 16 + l15) * 32 + qsw];
#pragma unroll
        for (int i = 0; i < 4; ++i)
#pragma unroll
            for (int j = 0; j < 2; ++j)
                acc[i][j] = __builtin_amdgcn_mfma_f32_16x16x32_bf16(af[i], bfr[j], acc[i][j], 0, 0, 0);
    }

#pragma unroll
    for (int i = 0; i < 4; ++i)
#pragma unroll
        for (int j = 0; j < 2; ++j)
#pragma unroll
            for (int r = 0; r < 4; ++r) {
                const int row = m0 + wm + i * 16 + quad * 4 + r;
                const int col = n0 + wn + j * 16 + l15;
                out[(size_t)row * Dm + col] = acc[i][j][r];
            }
}

// ------------------------- bf16 MFMA causal flash attention -------------------
// R19: 32 queries/wave (two 16-row Q fragments), 128 queries/block.
// grid (B*NH=32, 16); qt = 15 - blockIdx.y (longest first). KT=64 single
// buffer. Each kb/vb LDS read feeds 2 MFMAs (one per q-half) -> LDS traffic
// per unit work halved vs R18. S^T = K*Q^T swapped operands; fixed-max exp2
// softmax; chunk-swizzled K/V; cvt_pk P-pack; pointer-bump addressing.
__global__ __launch_bounds__(256) void attn_mfma(const unsigned short* __restrict__ Qb,
                                                 const unsigned short* __restrict__ Kb,
                                                 const unsigned short* __restrict__ VbT,
                                                 unsigned short* __restrict__ Yb) {
    const int bh = blockIdx.x;
    const int b = bh >> 4;
    const int h = bh & 15;
    const int qt = 15 - blockIdx.y;
    const int tid = threadIdx.x;
    const int wave = tid >> 6;
    const int lane = tid & 63;
    const int l15 = lane & 15;
    const int quad = lane >> 4;

    __shared__ unsigned short Ks0[64][32];   // [key][d 0..31]   (chunk-swizzled)
    __shared__ unsigned short Ks1[64][32];   // [key][d 32..63]  (chunk-swizzled)
    __shared__ unsigned short Vt0[64][32];   // [d][key 0..31]   (chunk-swizzled)
    __shared__ unsigned short Vt1[64][32];   // [d][key 32..63]  (chunk-swizzled)
    __shared__ unsigned short Ps[4][32][72]; // per-wave P [query 0..31][key]

    const size_t tok0 = (size_t)b * Tseq;
    const int colh = h * HD;

    const int qrow = qt * 128 + wave * 32;   // first of the wave's 32 queries

    const unsigned short* qbase = Qb + (tok0 + qrow) * Dm + colh;
    const bf16x8 qf00 = *(const bf16x8*)(qbase + (size_t)l15 * Dm + quad * 8);
    const bf16x8 qf01 = *(const bf16x8*)(qbase + (size_t)l15 * Dm + 32 + quad * 8);
    const bf16x8 qf10 = *(const bf16x8*)(qbase + (size_t)(16 + l15) * Dm + quad * 8);
    const bf16x8 qf11 = *(const bf16x8*)(qbase + (size_t)(16 + l15) * Dm + 32 + quad * 8);

    float l0 = 0.f, l1 = 0.f;                // denoms for query l15 (half0/half1)
    floatx4 o0[4], o1[4];
#pragma unroll
    for (int t = 0; t < 4; ++t) {
        o0[t] = (floatx4){0.f, 0.f, 0.f, 0.f};
        o1[t] = (floatx4){0.f, 0.f, 0.f, 0.f};
    }

    const int srow = tid >> 2;
    const int sc8 = (tid & 3) * 8;
    const int ssw = ((tid & 3) ^ ((srow >> 1) & 3)) * 8;
    const int qsw = (quad ^ ((l15 >> 1) & 3)) * 8;

    const unsigned short* krow = Kb + (tok0 + srow) * Dm + colh;
    const unsigned short* vrow = VbT + (size_t)bh * HD * Tseq + (size_t)srow * Tseq;

    const int niter = 2 * qt + 2;
    for (int it = 0; it < niter; ++it) {
        const int k0 = it * 64;
        __syncthreads();   // WAR: all waves done reading previous tile
        lds16(&Ks0[srow][sc8], krow + ssw);
        lds16(&Ks1[srow][sc8], krow + 32 + ssw);
        lds16(&Vt0[srow][sc8], vrow + ssw);
        lds16(&Vt1[srow][sc8], vrow + 32 + ssw);
        krow += 64 * Dm;
        vrow += 64;
        __syncthreads();   // vmcnt drained before barrier -> tile ready

        if (k0 > qrow + 31) continue;  // wave-uniform skip (keys all future)

        // ---- S^T (64 keys x 32 queries): A=K frag, B=Q frags (2 halves)
        floatx4 sf0[4], sf1[4];
        __builtin_amdgcn_s_setprio(1);
#pragma unroll
        for (int t = 0; t < 4; ++t) {
            const bf16x8 kb0 = *(const bf16x8*)&Ks0[t * 16 + l15][qsw];
            const bf16x8 kb1 = *(const bf16x8*)&Ks1[t * 16 + l15][qsw];
            floatx4 c0 = (floatx4){0.f, 0.f, 0.f, 0.f};
            floatx4 c1 = (floatx4){0.f, 0.f, 0.f, 0.f};
            c0 = __builtin_amdgcn_mfma_f32_16x16x32_bf16(kb0, qf00, c0, 0, 0, 0);
            c0 = __builtin_amdgcn_mfma_f32_16x16x32_bf16(kb1, qf01, c0, 0, 0, 0);
            c1 = __builtin_amdgcn_mfma_f32_16x16x32_bf16(kb0, qf10, c1, 0, 0, 0);
            c1 = __builtin_amdgcn_mfma_f32_16x16x32_bf16(kb1, qf11, c1, 0, 0, 0);
            sf0[t] = c0;   // row = key = t*16+quad*4+r, col = query = l15
            sf1[t] = c1;   // same, queries +16
        }
        __builtin_amdgcn_s_setprio(0);

        // ---- causal mask (diagonal tiles): key > query
        if (k0 + 63 > qrow) {
            const int ql = qrow + l15;
#pragma unroll
            for (int t = 0; t < 4; ++t)
#pragma unroll
                for (int r = 0; r < 4; ++r) {
                    const int kl = k0 + t * 16 + quad * 4 + r;
                    if (kl > ql) sf0[t][r] = -1.0e30f;
                }
        }
        if (k0 + 63 > qrow + 16) {
            const int ql = qrow + 16 + l15;
#pragma unroll
            for (int t = 0; t < 4; ++t)
#pragma unroll
                for (int r = 0; r < 4; ++r) {
                    const int kl = k0 + t * 16 + quad * 4 + r;
                    if (kl > ql) sf1[t][r] = -1.0e30f;
                }
        }

        // ---- p = exp2(s); l accumulate; Ps packed via cvt_pk (both halves)
#pragma unroll
        for (int t = 0; t < 4; ++t) {
            float p0 = __builtin_amdgcn_exp2f(sf0[t][0]);
            float p1 = __builtin_amdgcn_exp2f(sf0[t][1]);
            float p2 = __builtin_amdgcn_exp2f(sf0[t][2]);
            float p3 = __builtin_amdgcn_exp2f(sf0[t][3]);
            l0 += (p0 + p1) + (p2 + p3);
            unsigned int w0, w1;
            asm("v_cvt_pk_bf16_f32 %0, %1, %2" : "=v"(w0) : "v"(p0), "v"(p1));
            asm("v_cvt_pk_bf16_f32 %0, %1, %2" : "=v"(w1) : "v"(p2), "v"(p3));
            uint2 o; o.x = w0; o.y = w1;
            *(uint2*)&Ps[wave][l15][t * 16 + quad * 4] = o;
        }
#pragma unroll
        for (int t = 0; t < 4; ++t) {
            float p0 = __builtin_amdgcn_exp2f(sf1[t][0]);
            float p1 = __builtin_amdgcn_exp2f(sf1[t][1]);
            float p2 = __builtin_amdgcn_exp2f(sf1[t][2]);
            float p3 = __builtin_amdgcn_exp2f(sf1[t][3]);
            l1 += (p0 + p1) + (p2 + p3);
            unsigned int w0, w1;
            asm("v_cvt_pk_bf16_f32 %0, %1, %2" : "=v"(w0) : "v"(p0), "v"(p1));
            asm("v_cvt_pk_bf16_f32 %0, %1, %2" : "=v"(w1) : "v"(p2), "v"(p3));
            uint2 o; o.x = w0; o.y = w1;
            *(uint2*)&Ps[wave][16 + l15][t * 16 + quad * 4] = o;
        }

        // ---- PV: O (32 x 64) += P (32 x 64) @ V (64 x 64); vb shared
        const bf16x8 pa00 = *(const bf16x8*)&Ps[wave][l15][qsw? quad * 8 : quad * 8];
        const bf16x8 pa01 = *(const bf16x8*)&Ps[wave][l15][32 + quad * 8];
        const bf16x8 pa10 = *(const bf16x8*)&Ps[wave][16 + l15][quad * 8];
        const bf16x8 pa11 = *(const bf16x8*)&Ps[wave][16 + l15][32 + quad * 8];
        __builtin_amdgcn_s_setprio(1);
#pragma unroll
        for (int t = 0; t < 4; ++t) {
            const bf16x8 vb0 = *(const bf16x8*)&Vt0[t * 16 + l15][qsw];
            const bf16x8 vb1 = *(const bf16x8*)&Vt1[t * 16 + l15][qsw];
            o0[t] = __builtin_amdgcn_mfma_f32_16x16x32_bf16(pa00, vb0, o0[t], 0, 0, 0);
            o0[t] = __builtin_amdgcn_mfma_f32_16x16x32_bf16(pa01, vb1, o0[t], 0, 0, 0);
            o1[t] = __builtin_amdgcn_mfma_f32_16x16x32_bf16(pa10, vb0, o1[t], 0, 0, 0);
            o1[t] = __builtin_amdgcn_mfma_f32_16x16x32_bf16(pa11, vb1, o1[t], 0, 0, 0);
        }
        __builtin_amdgcn_s_setprio(0);
    }

    // ---- epilogue (per half): reduce l across quads, redistribute, scale.
    l0 += __shfl_xor(l0, 16);
    l0 += __shfl_xor(l0, 32);
    l1 += __shfl_xor(l1, 16);
    l1 += __shfl_xor(l1, 32);
    const float inv0 = 1.0f / l0;
    const float inv1 = 1.0f / l1;
    float inv0_r[4], inv1_r[4];
#pragma unroll
    for (int r = 0; r < 4; ++r) {
        inv0_r[r] = __shfl(inv0, (lane & 48) | (quad * 4 + r));
        inv1_r[r] = __shfl(inv1, (lane & 48) | (quad * 4 + r));
    }
#pragma unroll
    for (int t = 0; t < 4; ++t)
#pragma unroll
        for (int r = 0; r < 4; ++r) {
            const int q0 = qrow + quad * 4 + r;
            const int q1 = qrow + 16 + quad * 4 + r;
            Yb[(tok0 + q0) * Dm + colh + t * 16 + l15] = f2bf(o0[t][r] * inv0_r[r]);
            Yb[(tok0 + q1) * Dm + colh + t * 16 + l15] = f2bf(o1[t][r] * inv1_r[r]);
        }
}

// ------------------------------- launch --------------------------------------
extern "C" void kernel_launch(void* const* d_in, const int* in_sizes, int n_in,
                              void* d_out, int out_size, void* d_ws, size_t ws_size,
                              hipStream_t stream) {
    const float* x  = (const float*)d_in[0];
    const float* Wq = (const float*)d_in[1];
    const float* Wk = (const float*)d_in[2];
    const float* Wv = (const float*)d_in[3];
    const float* Wo = (const float*)d_in[4];
    float* out = (float*)d_out;

    const int M = Bsz * Tseq;  // 4096
    char* ws = (char*)d_ws;
    unsigned short* xb  = (unsigned short*)(ws);
    unsigned short* Wqt = (unsigned short*)(ws + (((size_t)8)  << 20));
    unsigned short* Wkt = (unsigned short*)(ws + (((size_t)10) << 20));
    unsigned short* Wvt = (unsigned short*)(ws + (((size_t)12) << 20));
    unsigned short* Wot = (unsigned short*)(ws + (((size_t)14) << 20));
    unsigned short* Qb  = (unsigned short*)(ws + (((size_t)16) << 20));
    unsigned short* Kb  = (unsigned short*)(ws + (((size_t)24) << 20));
    unsigned short* VbT = (unsigned short*)(ws + (((size_t)32) << 20));
    unsigned short* Yb  = (unsigned short*)(ws + (((size_t)40) << 20));

    dim3 blk(256);
    hipLaunchKernelGGL(prep, dim3(16, 16, 20), blk, 0, stream,
                       x, Wq, Wk, Wv, Wo, xb, Wqt, Wkt, Wvt, Wot);

    hipLaunchKernelGGL(gemm_qkv, dim3(Dm / 128, M / 128, 3), blk, 0, stream,
                       xb, Wqt, Wkt, Wvt, Qb, Kb, VbT);

    hipLaunchKernelGGL(attn_mfma, dim3(Bsz * NH, 16), blk, 0, stream, Qb, Kb, VbT, Yb);

    hipLaunchKernelGGL(gemm_out, dim3(Dm / 64, M / 128), blk, 0, stream, Yb, Wot, out);
}

// Round 8
// 168.811 us; speedup vs baseline: 1.0864x; 1.0864x over previous
//
#include <hip/hip_runtime.h>
#include <hip/hip_bf16.h>
#include <math.h>

// B=2, T=2048, D=1024, H=16, hd=64. fp32 in/out.
// Round 21: split-K attention (flash-decoding), memory-safe layout.
// R20's 65MB workspace exceeded the proven 48MB footprint -> suspected OOB
// writes killed the container. Fix: partials live in regions DEAD after
// gemm_qkv (in-stream ordering makes this safe):
//   Op (bf16, 1024 slots x 64q x 64d = 8MB)  -> over xb@0
//   lp (fp32, 1024 slots x 64 = 256KB)       -> over Wqt@8
// Total ws stays 48MB. Theory unchanged (critical-path model from R13-R19:
// attn time == longest block's serial chain; fixed-max softmax => partials
// sum exactly): qt>=16 tiles split into 2 key-chunks (<=16 units each) on
// independent blocks; attn_merge does Y=(O0+O1)/(l0+l1). Longest chain
// 32->16 units. Per-unit structure = R18 (16 q/wave; R19 32q/wave regressed).
// Ledger: R14 swz free; R15 dbuf null; R16 BK=64 regress; cvt_pk kept;
// R17 GEMM swz kept; R18 XCD swz kept; occupancy & LDS-intensity FALSIFIED.
// ws (MB): xb@0[8]/Op  Wqt@8[2]/lp  Wkt@10[2] Wvt@12[2] Wot@14[2]
// Qb@16[8] Kb@24[8] VbT@32[8] Yb@40[8] = 48 MB.

#define Bsz  2
#define Tseq 2048
#define Dm   1024
#define NH   16
#define HD   64

typedef short bf16x8 __attribute__((ext_vector_type(8)));
typedef float floatx4 __attribute__((ext_vector_type(4)));

__device__ __forceinline__ unsigned short f2bf(float f) {
    __hip_bfloat16 h = __float2bfloat16(f);
    return *reinterpret_cast<unsigned short*>(&h);
}

__device__ __forceinline__ float bf2f(unsigned short u) {
    unsigned int x = ((unsigned int)u) << 16;
    return __builtin_bit_cast(float, x);
}

// async global->LDS, 16 B per lane. LDS dest must be waveBase + lane*16.
__device__ __forceinline__ void lds16(unsigned short* lds, const unsigned short* g) {
    __builtin_amdgcn_global_load_lds(
        (const __attribute__((address_space(1))) void*)g,
        (__attribute__((address_space(3))) void*)lds, 16, 0, 0);
}

// ---------------- prep: W transpose-cast (z<4) + x cast (z>=4) ---------------
__global__ __launch_bounds__(256) void prep(const float* __restrict__ x,
                                            const float* __restrict__ W0,
                                            const float* __restrict__ W1,
                                            const float* __restrict__ W2,
                                            const float* __restrict__ W3,
                                            unsigned short* __restrict__ xb,
                                            unsigned short* __restrict__ T0,
                                            unsigned short* __restrict__ T1,
                                            unsigned short* __restrict__ T2,
                                            unsigned short* __restrict__ T3) {
    __shared__ float t[64][65];
    const int z = blockIdx.z;
    if (z >= 4) {  // cast x
        const int bi = (z - 4) * 256 + blockIdx.y * 16 + blockIdx.x;
        const size_t i = (size_t)bi * 256 + threadIdx.x;
        const float4 v = ((const float4*)x)[i];
        ushort4 o;
        o.x = f2bf(v.x); o.y = f2bf(v.y); o.z = f2bf(v.z); o.w = f2bf(v.w);
        ((ushort4*)xb)[i] = o;
        return;
    }
    const float* W = (z == 0) ? W0 : (z == 1) ? W1 : (z == 2) ? W2 : W3;
    unsigned short* T = (z == 0) ? T0 : (z == 1) ? T1 : (z == 2) ? T2 : T3;
    const int k0 = blockIdx.y * 64, n0 = blockIdx.x * 64;
    const int row = threadIdx.x >> 6, col = threadIdx.x & 63;
#pragma unroll
    for (int p = 0; p < 16; ++p)
        t[p * 4 + row][col] = W[(size_t)(k0 + p * 4 + row) * Dm + n0 + col];
    __syncthreads();
#pragma unroll
    for (int p = 0; p < 16; ++p)
        T[(size_t)(n0 + p * 4 + row) * Dm + k0 + col] = f2bf(t[col][p * 4 + row]);
}

// ---------------- bf16 MFMA GEMM mainloop (128x128, BK=32, swizzled) ---------
__device__ __forceinline__ void gemm128_mainloop(const unsigned short* __restrict__ A,
                                                 const unsigned short* __restrict__ Bt,
                                                 int K, int m0, int n0,
                                                 unsigned short* As, unsigned short* Bs,
                                                 floatx4 acc[4][4]) {
    const int tid = threadIdx.x;
    const int lane = tid & 63, wave = tid >> 6;
    const int l15 = lane & 15, quad = lane >> 4;
    const int wm = (wave >> 1) * 64, wn = (wave & 1) * 64;

    const int qsw = (quad ^ ((l15 >> 1) & 3)) * 8;

    for (int k0 = 0; k0 < K; k0 += 32) {
        __syncthreads();
#pragma unroll
        for (int c = 0; c < 2; ++c) {
            const int idx = c * 256 + tid;
            const int row = idx >> 2, kc = (idx & 3) * 8;
            const int sk = ((idx & 3) ^ ((row >> 1) & 3)) * 8;
            lds16(&As[row * 32 + kc], A + (size_t)(m0 + row) * K + k0 + sk);
            lds16(&Bs[row * 32 + kc], Bt + (size_t)(n0 + row) * K + k0 + sk);
        }
        __syncthreads();
        bf16x8 af[4], bfr[4];
#pragma unroll
        for (int i = 0; i < 4; ++i)
            af[i] = *(const bf16x8*)&As[(wm + i * 16 + l15) * 32 + qsw];
#pragma unroll
        for (int j = 0; j < 4; ++j)
            bfr[j] = *(const bf16x8*)&Bs[(wn + j * 16 + l15) * 32 + qsw];
#pragma unroll
        for (int i = 0; i < 4; ++i)
#pragma unroll
            for (int j = 0; j < 4; ++j)
                acc[i][j] = __builtin_amdgcn_mfma_f32_16x16x32_bf16(af[i], bfr[j], acc[i][j], 0, 0, 0);
    }
}

// QKV split over grid.z: z selects weight/output. Q scaled 0.125*log2e.
// z==2 (V) writes the transposed VbT [bh][d][tok] directly. XCD-swizzled.
__global__ __launch_bounds__(256) void gemm_qkv(const unsigned short* __restrict__ xb,
                                                const unsigned short* __restrict__ Wqt,
                                                const unsigned short* __restrict__ Wkt,
                                                const unsigned short* __restrict__ Wvt,
                                                unsigned short* __restrict__ Qb,
                                                unsigned short* __restrict__ Kb,
                                                unsigned short* __restrict__ VbT) {
    __shared__ unsigned short As[128 * 32];
    __shared__ unsigned short Bs[128 * 32];
    const int z = blockIdx.z;
    const unsigned short* Bt = (z == 0) ? Wqt : (z == 1) ? Wkt : Wvt;
    const float scale = (z == 0) ? (0.125f * 1.4426950408889634f) : 1.0f;

    const int wg = blockIdx.x + 8 * blockIdx.y;   // 0..255 within z-plane
    const int m_idx = (wg & 7) * 4 + (wg >> 6);   // 0..31
    const int n_idx = (wg >> 3) & 7;              // 0..7
    const int m0 = m_idx * 128, n0 = n_idx * 128;

    floatx4 acc[4][4];
#pragma unroll
    for (int i = 0; i < 4; ++i)
#pragma unroll
        for (int j = 0; j < 4; ++j) acc[i][j] = (floatx4){0.f, 0.f, 0.f, 0.f};

    gemm128_mainloop(xb, Bt, Dm, m0, n0, As, Bs, acc);

    const int lane = threadIdx.x & 63, wave = threadIdx.x >> 6;
    const int l15 = lane & 15, quad = lane >> 4;
    const int wm = (wave >> 1) * 64, wn = (wave & 1) * 64;

    if (z == 2) {
#pragma unroll
        for (int i = 0; i < 4; ++i)
#pragma unroll
            for (int j = 0; j < 4; ++j) {
                const int col = n0 + wn + j * 16 + l15;
                const int hh = col >> 6, dd = col & 63;
                const int tok = m0 + wm + i * 16 + quad * 4;
                const int bb = tok >> 11, tl = tok & (Tseq - 1);
                ushort4 o;
                o.x = f2bf(acc[i][j][0]); o.y = f2bf(acc[i][j][1]);
                o.z = f2bf(acc[i][j][2]); o.w = f2bf(acc[i][j][3]);
                *(ushort4*)&VbT[((size_t)((bb * NH + hh) * HD + dd)) * Tseq + tl] = o;
            }
        return;
    }
    unsigned short* C = (z == 0) ? Qb : Kb;
#pragma unroll
    for (int i = 0; i < 4; ++i)
#pragma unroll
        for (int j = 0; j < 4; ++j)
#pragma unroll
            for (int r = 0; r < 4; ++r) {
                const int row = m0 + wm + i * 16 + quad * 4 + r;
                const int col = n0 + wn + j * 16 + l15;
                C[(size_t)row * Dm + col] = f2bf(acc[i][j][r] * scale);
            }
}

// Final GEMM: Yb @ Wo -> fp32 out. 128x64 tiles, BK=32, swizzled LDS,
// XCD-swizzled block map.
__global__ __launch_bounds__(256) void gemm_out(const unsigned short* __restrict__ Yb,
                                                const unsigned short* __restrict__ Wot,
                                                float* __restrict__ out) {
    __shared__ unsigned short As[128 * 32];
    __shared__ unsigned short Bs[64 * 32];
    const int wg = blockIdx.x + 16 * blockIdx.y;  // 0..511
    const int m_idx = (wg & 7) * 4 + (wg >> 7);   // 0..31
    const int n_idx = (wg >> 3) & 15;             // 0..15
    const int m0 = m_idx * 128, n0 = n_idx * 64;
    const int tid = threadIdx.x;
    const int lane = tid & 63, wave = tid >> 6;
    const int l15 = lane & 15, quad = lane >> 4;
    const int wm = (wave >> 1) * 64, wn = (wave & 1) * 32;
    const int qsw = (quad ^ ((l15 >> 1) & 3)) * 8;

    floatx4 acc[4][2];
#pragma unroll
    for (int i = 0; i < 4; ++i)
#pragma unroll
        for (int j = 0; j < 2; ++j) acc[i][j] = (floatx4){0.f, 0.f, 0.f, 0.f};

    for (int k0 = 0; k0 < Dm; k0 += 32) {
        __syncthreads();
#pragma unroll
        for (int c = 0; c < 2; ++c) {
            const int idx = c * 256 + tid;
            const int row = idx >> 2, kc = (idx & 3) * 8;
            const int sk = ((idx & 3) ^ ((row >> 1) & 3)) * 8;
            lds16(&As[row * 32 + kc], Yb + (size_t)(m0 + row) * Dm + k0 + sk);
        }
        {
            const int row = tid >> 2, kc = (tid & 3) * 8;
            const int sk = ((tid & 3) ^ ((row >> 1) & 3)) * 8;
            lds16(&Bs[row * 32 + kc], Wot + (size_t)(n0 + row) * Dm + k0 + sk);
        }
        __syncthreads();
        bf16x8 af[4], bfr[2];
#pragma unroll
        for (int i = 0; i < 4; ++i)
            af[i] = *(const bf16x8*)&As[(wm + i * 16 + l15) * 32 + qsw];
#pragma unroll
        for (int j = 0; j < 2; ++j)
            bfr[j] = *(const bf16x8*)&Bs[(wn + j * 16 + l15) * 32 + qsw];
#pragma unroll
        for (int i = 0; i < 4; ++i)
#pragma unroll
            for (int j = 0; j < 2; ++j)
                acc[i][j] = __builtin_amdgcn_mfma_f32_16x16x32_bf16(af[i], bfr[j], acc[i][j], 0, 0, 0);
    }

#pragma unroll
    for (int i = 0; i < 4; ++i)
#pragma unroll
        for (int j = 0; j < 2; ++j)
#pragma unroll
            for (int r = 0; r < 4; ++r) {
                const int row = m0 + wm + i * 16 + quad * 4 + r;
                const int col = n0 + wn + j * 16 + l15;
                out[(size_t)row * Dm + col] = acc[i][j][r];
            }
}

// ------------------------- bf16 MFMA causal flash attention -------------------
// R21 split-K: grid (32 bh, 48). blockIdx.y maps:
//   y in [0,16):  qt = 16+y,  chunk0: key-units 0..15   -> bf16 partials
//   y in [16,32): qt = 47-y,  chunk1: key-units 16..qt  -> bf16 partials
//   y in [32,48): qt = 47-y (<16), full: units 0..qt    -> Yb directly
// Per-unit structure = R18 (16 q/wave, KT=64, single buffer, chunk-swizzled
// K/V, cvt_pk P-pack, fixed-max exp2 softmax). Max serial chain: 16 units.
// Fixed-max softmax => partials sum exactly (no rescale).
__global__ __launch_bounds__(256) void attn_mfma(const unsigned short* __restrict__ Qb,
                                                 const unsigned short* __restrict__ Kb,
                                                 const unsigned short* __restrict__ VbT,
                                                 unsigned short* __restrict__ Yb,
                                                 unsigned short* __restrict__ Op,
                                                 float* __restrict__ lp) {
    const int bh = blockIdx.x;
    const int b = bh >> 4;
    const int h = bh & 15;
    const int y = blockIdx.y;

    int qt, itStart, itEnd, chunk;
    bool partial;
    if (y < 16)      { qt = 16 + y; chunk = 0; itStart = 0;  itEnd = 16;     partial = true;  }
    else if (y < 32) { qt = 47 - y; chunk = 1; itStart = 16; itEnd = qt + 1; partial = true;  }
    else             { qt = 47 - y; chunk = 0; itStart = 0;  itEnd = qt + 1; partial = false; }

    const int tid = threadIdx.x;
    const int wave = tid >> 6;
    const int lane = tid & 63;
    const int l15 = lane & 15;
    const int quad = lane >> 4;

    __shared__ unsigned short Ks0[64][32];  // [key][d 0..31]   (chunk-swizzled)
    __shared__ unsigned short Ks1[64][32];  // [key][d 32..63]  (chunk-swizzled)
    __shared__ unsigned short Vt0[64][32];  // [d][key 0..31]   (chunk-swizzled)
    __shared__ unsigned short Vt1[64][32];  // [d][key 32..63]  (chunk-swizzled)
    __shared__ unsigned short Ps[4][16][72];  // per-wave P [query][key]

    const size_t tok0 = (size_t)b * Tseq;
    const int colh = h * HD;

    const int qrow = qt * 64 + wave * 16;

    const unsigned short* qptr = Qb + (tok0 + qrow + l15) * Dm + colh + quad * 8;
    const bf16x8 qf0 = *(const bf16x8*)(qptr);
    const bf16x8 qf1 = *(const bf16x8*)(qptr + 32);

    float l_lane = 0.f;                        // denom for query l15
    floatx4 o_acc[4];
#pragma unroll
    for (int t = 0; t < 4; ++t) o_acc[t] = (floatx4){0.f, 0.f, 0.f, 0.f};

    const int srow = tid >> 2;
    const int sc8 = (tid & 3) * 8;
    const int ssw = ((tid & 3) ^ ((srow >> 1) & 3)) * 8;
    const int qsw = (quad ^ ((l15 >> 1) & 3)) * 8;

    // staging pointers, bumped per iteration (64 tokens / 64 key-cols)
    const unsigned short* krow = Kb + (tok0 + itStart * 64 + srow) * Dm + colh;
    const unsigned short* vrow = VbT + (size_t)bh * HD * Tseq + (size_t)srow * Tseq + itStart * 64;

    for (int it = itStart; it < itEnd; ++it) {
        const int k0 = it * 64;
        __syncthreads();   // WAR: all waves done reading previous tile
        lds16(&Ks0[srow][sc8], krow + ssw);
        lds16(&Ks1[srow][sc8], krow + 32 + ssw);
        lds16(&Vt0[srow][sc8], vrow + ssw);
        lds16(&Vt1[srow][sc8], vrow + 32 + ssw);
        krow += 64 * Dm;
        vrow += 64;
        __syncthreads();   // vmcnt drained before barrier -> tile ready

        // ---- S^T (64 keys x 16 queries): A=K frag, B=Q frag
        floatx4 sf[4];
        __builtin_amdgcn_s_setprio(1);
#pragma unroll
        for (int t = 0; t < 4; ++t) {
            floatx4 c = (floatx4){0.f, 0.f, 0.f, 0.f};
            const bf16x8 kb0 = *(const bf16x8*)&Ks0[t * 16 + l15][qsw];
            const bf16x8 kb1 = *(const bf16x8*)&Ks1[t * 16 + l15][qsw];
            c = __builtin_amdgcn_mfma_f32_16x16x32_bf16(kb0, qf0, c, 0, 0, 0);
            c = __builtin_amdgcn_mfma_f32_16x16x32_bf16(kb1, qf1, c, 0, 0, 0);
            sf[t] = c;   // row = key = t*16 + quad*4 + r, col = query = l15
        }
        __builtin_amdgcn_s_setprio(0);

        // ---- causal mask (diagonal tile): key > query
        if (k0 + 63 > qrow) {
            const int ql = qrow + l15;
#pragma unroll
            for (int t = 0; t < 4; ++t)
#pragma unroll
                for (int r = 0; r < 4; ++r) {
                    const int kl = k0 + t * 16 + quad * 4 + r;
                    if (kl > ql) sf[t][r] = -1.0e30f;
                }
        }

        // ---- p = exp2(s); l (scalar) accumulate; Ps packed via cvt_pk
#pragma unroll
        for (int t = 0; t < 4; ++t) {
            float p0 = __builtin_amdgcn_exp2f(sf[t][0]);
            float p1 = __builtin_amdgcn_exp2f(sf[t][1]);
            float p2 = __builtin_amdgcn_exp2f(sf[t][2]);
            float p3 = __builtin_amdgcn_exp2f(sf[t][3]);
            l_lane += (p0 + p1) + (p2 + p3);
            unsigned int w0, w1;
            asm("v_cvt_pk_bf16_f32 %0, %1, %2" : "=v"(w0) : "v"(p0), "v"(p1));
            asm("v_cvt_pk_bf16_f32 %0, %1, %2" : "=v"(w1) : "v"(p2), "v"(p3));
            uint2 o; o.x = w0; o.y = w1;
            *(uint2*)&Ps[wave][l15][t * 16 + quad * 4] = o;
        }

        // ---- PV: O (16 x 64) += P (16 x 64) @ V (64 x 64)
        const bf16x8 pa0 = *(const bf16x8*)&Ps[wave][l15][quad * 8];
        const bf16x8 pa1 = *(const bf16x8*)&Ps[wave][l15][32 + quad * 8];
        __builtin_amdgcn_s_setprio(1);
#pragma unroll
        for (int t = 0; t < 4; ++t) {
            const bf16x8 vb0 = *(const bf16x8*)&Vt0[t * 16 + l15][qsw];
            const bf16x8 vb1 = *(const bf16x8*)&Vt1[t * 16 + l15][qsw];
            o_acc[t] = __builtin_amdgcn_mfma_f32_16x16x32_bf16(pa0, vb0, o_acc[t], 0, 0, 0);
            o_acc[t] = __builtin_amdgcn_mfma_f32_16x16x32_bf16(pa1, vb1, o_acc[t], 0, 0, 0);
        }
        __builtin_amdgcn_s_setprio(0);
    }

    // ---- l reduce across the 4 quads (all lanes end with l for query l15)
    l_lane += __shfl_xor(l_lane, 16);
    l_lane += __shfl_xor(l_lane, 32);

    if (partial) {
        // bf16 partials: Op [slot][64 q][64 d], lp [slot][64 q]
        const size_t slot = ((size_t)(bh * 16 + (qt - 16)) * 2 + chunk);
        unsigned short* Opb = Op + slot * 4096;
        float* lpb = lp + slot * 64;
#pragma unroll
        for (int t = 0; t < 4; ++t)
#pragma unroll
            for (int r = 0; r < 4; ++r)
                Opb[(wave * 16 + quad * 4 + r) * 64 + t * 16 + l15] = f2bf(o_acc[t][r]);
        if (quad == 0) lpb[wave * 16 + l15] = l_lane;
        return;
    }

    const float inv_q = 1.0f / l_lane;         // inv denom for query l15
    float inv_r[4];
#pragma unroll
    for (int r = 0; r < 4; ++r)
        inv_r[r] = __shfl(inv_q, (lane & 48) | (quad * 4 + r));
#pragma unroll
    for (int t = 0; t < 4; ++t)
#pragma unroll
        for (int r = 0; r < 4; ++r) {
            const int q = qrow + quad * 4 + r;
            Yb[(tok0 + q) * Dm + colh + t * 16 + l15] = f2bf(o_acc[t][r] * inv_r[r]);
        }
}

// Merge: Y = (O0+O1)/(l0+l1) for qt in [16,32). grid (32*16), 256 thr.
__global__ __launch_bounds__(256) void attn_merge(const unsigned short* __restrict__ Op,
                                                  const float* __restrict__ lp,
                                                  unsigned short* __restrict__ Yb) {
    const int bh = blockIdx.x >> 4;
    const int qh = blockIdx.x & 15;
    const int qt = 16 + qh;
    const int b = bh >> 4, h = bh & 15;
    const int tid = threadIdx.x;
    const int q = tid >> 2;            // 0..63
    const int d0 = (tid & 3) * 16;     // 0,16,32,48

    const size_t slot = ((size_t)(bh * 16 + qh) * 2);
    const unsigned short* O0 = Op + slot * 4096;
    const unsigned short* O1 = O0 + 4096;
    const float* l0 = lp + slot * 64;
    const float* l1 = l0 + 64;

    const float inv = 1.0f / (l0[q] + l1[q]);
    unsigned short* dst = Yb + ((size_t)b * Tseq + qt * 64 + q) * Dm + h * HD + d0;
    const int src = q * 64 + d0;
#pragma unroll
    for (int c = 0; c < 4; ++c) {
        const ushort4 a = *(const ushort4*)&O0[src + c * 4];
        const ushort4 bb = *(const ushort4*)&O1[src + c * 4];
        ushort4 o;
        o.x = f2bf((bf2f(a.x) + bf2f(bb.x)) * inv);
        o.y = f2bf((bf2f(a.y) + bf2f(bb.y)) * inv);
        o.z = f2bf((bf2f(a.z) + bf2f(bb.z)) * inv);
        o.w = f2bf((bf2f(a.w) + bf2f(bb.w)) * inv);
        *(ushort4*)&dst[c * 4] = o;
    }
}

// ------------------------------- launch --------------------------------------
extern "C" void kernel_launch(void* const* d_in, const int* in_sizes, int n_in,
                              void* d_out, int out_size, void* d_ws, size_t ws_size,
                              hipStream_t stream) {
    const float* x  = (const float*)d_in[0];
    const float* Wq = (const float*)d_in[1];
    const float* Wk = (const float*)d_in[2];
    const float* Wv = (const float*)d_in[3];
    const float* Wo = (const float*)d_in[4];
    float* out = (float*)d_out;

    const int M = Bsz * Tseq;  // 4096
    char* ws = (char*)d_ws;
    unsigned short* xb  = (unsigned short*)(ws);
    unsigned short* Wqt = (unsigned short*)(ws + (((size_t)8)  << 20));
    unsigned short* Wkt = (unsigned short*)(ws + (((size_t)10) << 20));
    unsigned short* Wvt = (unsigned short*)(ws + (((size_t)12) << 20));
    unsigned short* Wot = (unsigned short*)(ws + (((size_t)14) << 20));
    unsigned short* Qb  = (unsigned short*)(ws + (((size_t)16) << 20));
    unsigned short* Kb  = (unsigned short*)(ws + (((size_t)24) << 20));
    unsigned short* VbT = (unsigned short*)(ws + (((size_t)32) << 20));
    unsigned short* Yb  = (unsigned short*)(ws + (((size_t)40) << 20));
    // partial buffers reuse regions dead after gemm_qkv (stream-ordered):
    unsigned short* Op = xb;                       // 8 MB (1024 slots x 8KB)
    float* lp = (float*)Wqt;                       // 256 KB (1024 slots x 256B)

    dim3 blk(256);
    hipLaunchKernelGGL(prep, dim3(16, 16, 20), blk, 0, stream,
                       x, Wq, Wk, Wv, Wo, xb, Wqt, Wkt, Wvt, Wot);

    hipLaunchKernelGGL(gemm_qkv, dim3(Dm / 128, M / 128, 3), blk, 0, stream,
                       xb, Wqt, Wkt, Wvt, Qb, Kb, VbT);

    hipLaunchKernelGGL(attn_mfma, dim3(Bsz * NH, 48), blk, 0, stream,
                       Qb, Kb, VbT, Yb, Op, lp);

    hipLaunchKernelGGL(attn_merge, dim3(Bsz * NH * 16), blk, 0, stream, Op, lp, Yb);

    hipLaunchKernelGGL(gemm_out, dim3(Dm / 64, M / 128), blk, 0, stream, Yb, Wot, out);
}